// Round 12
// baseline (2451.422 us; speedup 1.0000x reference)
//
#include <hip/hip_runtime.h>

typedef unsigned int uint;
typedef unsigned short ushort;
typedef unsigned long long ull;

#define NB 16
#define NN 4096
#define NS 1024
#define NK 32
#define CIN0 67
#define NPTS (NB*NS*NK)           // 524288
#define NROWS (NB*NN)             // 65536 source rows
#define BN_EPS 1e-5f
#define INV_NPTS (1.0f/524288.0f) // exact power of two

// transposed-weight offsets inside wT (floats)
#define W0T_OFF 0      // [67][64]  = 4288
#define W1T_OFF 4288   // [64][64]  = 4096
#define W2T_OFF 8384   // [64][128] = 8192
#define WT_TOTAL 16576

// ================================================================ FPS v8
// 2 waves (128 threads), 32 pts/lane. Shorter cross-wave tail than r9's
// 4-wave version (2-entry merge, less barrier skew) at ~2x per-wave issue --
// net win if (as measured r9) the tail dominates. ~180 VGPR: no spill (r8's
// failure was 64 pts/lane at ~290). Same contract-off arithmetic, same
// ordered-slot strict-> tree (first-occurrence ties), same u64-key DPP
// reduce (validated r7/r9) with coord-attach.
#define FPS_T 128
#define PPT (NN / FPS_T) // 32

// dpp_ctrl: row_ror:N = 0x120+N ; row_bcast15 = 0x142 ; row_bcast31 = 0x143
#define KMAX_STEP(K, CTRL) do { \
    uint _lo = (uint)(K), _hi = (uint)((K) >> 32); \
    uint _nlo = (uint)__builtin_amdgcn_update_dpp(0, (int)_lo, (CTRL), 0xF, 0xF, true); \
    uint _nhi = (uint)__builtin_amdgcn_update_dpp(0, (int)_hi, (CTRL), 0xF, 0xF, true); \
    ull _nk = ((ull)_nhi << 32) | _nlo; \
    if (_nk > (K)) (K) = _nk; \
  } while (0)

__global__ __launch_bounds__(FPS_T) void fps_kernel(
    const float* __restrict__ xyz, float* __restrict__ centers,
    float* __restrict__ out_newxyz)
{
#pragma clang fp contract(off)
  __shared__ float4 sxyz[NN];                    // 64 KB
  __shared__ int sfar[NS];
  __shared__ __align__(16) uint2  sk[2][2];
  __shared__ __align__(16) float4 sc[2][2];
  const int b = blockIdx.x;
  const int tid = threadIdx.x;
  const int lane = tid & 63;
  const int wv = tid >> 6;
  const float* xb = xyz + (size_t)b * NN * 3;
  for (int i = tid; i < NN; i += FPS_T)
    sxyz[i] = make_float4(xb[i*3+0], xb[i*3+1], xb[i*3+2], 0.f);
  __syncthreads();
  float px[PPT], py[PPT], pz[PPT], dist[PPT];
  const int base = tid * PPT;
#pragma unroll
  for (int j = 0; j < PPT; ++j) {
    float4 P = sxyz[base+j];
    px[j] = P.x; py[j] = P.y; pz[j] = P.z;
    dist[j] = 1e10f;
  }
  float4 C0 = sxyz[0];
  float cx = C0.x, cy = C0.y, cz = C0.z;
  if (tid == 0) sfar[0] = 0;

  for (int it = 1; it < NS; ++it) {
    // distance update (independent per point)
#pragma unroll
    for (int j = 0; j < PPT; ++j) {
      float dx = px[j]-cx, dy = py[j]-cy, dz = pz[j]-cz;
      float d = (dx*dx + dy*dy) + dz*dz;
      float dd = dist[j];
      dist[j] = d < dd ? d : dd;
    }
    // local argmax tree over 32 (left operand lower index -> strict >;
    // ordered slots => first-occurrence tie semantics)
    float v[16]; int id[16];
#pragma unroll
    for (int j = 0; j < 16; ++j) {
      bool t = dist[2*j+1] > dist[2*j];
      v[j] = t ? dist[2*j+1] : dist[2*j];
      id[j] = base + (t ? 2*j+1 : 2*j);
    }
#pragma unroll
    for (int w = 8; w >= 1; w >>= 1) {
#pragma unroll
      for (int j = 0; j < w; ++j) {
        bool t = v[2*j+1] > v[2*j];
        v[j] = t ? v[2*j+1] : v[2*j];
        id[j] = t ? id[2*j+1] : id[2*j];
      }
    }
    // wave reduce on packed u64 key
    ull key = ((ull)__float_as_uint(v[0]) << 32) | (uint)(~id[0]);
    KMAX_STEP(key, 0x121);
    KMAX_STEP(key, 0x122);
    KMAX_STEP(key, 0x124);
    KMAX_STEP(key, 0x128);
    KMAX_STEP(key, 0x142);
    KMAX_STEP(key, 0x143);   // full-wave max in lanes 48-63
    const int pb = it & 1;
    if (lane == 63) {
      int iw = (int)(~(uint)key);
      float4 CW = sxyz[iw];               // pre-barrier: off the merge tail
      sk[pb][wv] = make_uint2((uint)key, (uint)(key >> 32));
      sc[pb][wv] = CW;
    }
    __syncthreads();
    // 2-entry merge: single u64 compare
    uint4 e01 = *(const uint4*)&sk[pb][0];
    ull k0 = ((ull)e01.y << 32) | e01.x;
    ull k1 = ((ull)e01.w << 32) | e01.z;
    float4 c0 = sc[pb][0], c1 = sc[pb][1];
    ull kb = k0; float4 C = c0;
    if (k1 > kb) { kb = k1; C = c1; }
    cx = C.x; cy = C.y; cz = C.z;
    if (tid == 0) sfar[it] = (int)(~(uint)kb);
  }
  __syncthreads();
  for (int s = tid; s < NS; s += FPS_T) {
    int f = sfar[s];
    float4 C = sxyz[f];
    size_t o = ((size_t)b * NS + s) * 3;
    centers[o] = C.x; centers[o+1] = C.y; centers[o+2] = C.z;
    out_newxyz[o] = C.x; out_newxyz[o+1] = C.y; out_newxyz[o+2] = C.z;
  }
}

// ================================================================ ball query v2 (validated r6)
#define BPAD(i) ((i) + ((i)>>6))
__global__ __launch_bounds__(256,2) void ball_kernel(
    const float* __restrict__ xyz, const float* __restrict__ centers,
    int* __restrict__ group_idx)
{
#pragma clang fp contract(off)
  __shared__ float sx[4160], sy[4160], sz[4160], sq[4160];  // 65 KB
  const int bid = blockIdx.x;            // 1024 blocks: 64 per batch
  const int b = bid >> 6;
  const int c0 = (bid & 63) << 4;        // 16 centers per block
  const int tid = threadIdx.x;
  const int lane = tid & 63;
  const int wave = tid >> 6;
  const float* xb = xyz + (size_t)b * NN * 3;
  for (int i = tid; i < NN; i += 256) {
    float x = xb[i*3+0], y = xb[i*3+1], z = xb[i*3+2];
    int a = BPAD(i);
    sx[a] = x; sy[a] = y; sz[a] = z;
    sq[a] = (x*x + y*y) + z*z;
  }
  __syncthreads();
  const int a0 = lane * 65;              // BPAD(lane*64)
#pragma unroll 1
  for (int r = 0; r < 4; ++r) {
    const int s = c0 + wave*4 + r;
    const size_t co = ((size_t)b * NS + s) * 3;
    const float cx = centers[co], cy = centers[co+1], cz = centers[co+2];
    const float csq = (cx*cx + cy*cy) + cz*cz;
    unsigned long long mask = 0ull;
#pragma unroll 8
    for (int j = 0; j < 64; ++j) {
      const float dot = (cx*sx[a0+j] + cy*sy[a0+j]) + cz*sz[a0+j];
      const float dist = (csq + sq[a0+j]) - 2.0f*dot;
      mask |= ((unsigned long long)(dist <= 0.25f)) << j;
    }
    int cnt = __popcll(mask);
    int inc = cnt;
#pragma unroll
    for (int m = 1; m < 64; m <<= 1) {
      int o = __shfl_up(inc, m);
      if (lane >= m) inc += o;
    }
    const int pre = inc - cnt;
    const int total = __shfl(inc, 63);
    unsigned long long bal = __ballot(cnt > 0);
    int fl = __ffsll(bal) - 1;
    int myfirst = cnt ? (lane << 6) + __ffsll(mask) - 1 : 0;
    int firstG = __shfl(myfirst, fl);
    int* out = group_idx + ((size_t)b * NS + s) * NK;
    if (pre < NK && cnt) {
      int k = pre;
      unsigned long long m2 = mask;
      while (m2 && k < NK) {
        int j = __ffsll(m2) - 1;
        out[k++] = (lane << 6) + j;
        m2 &= m2 - 1;
      }
    }
    if (total < NK) {
      for (int q2 = total + lane; q2 < NK; q2 += 64) out[q2] = firstG;
    }
  }
}

// ================================================================ prep
__global__ __launch_bounds__(256) void prep_kernel(
    const float* __restrict__ w0, const float* __restrict__ w1,
    const float* __restrict__ w2, float* __restrict__ wT)
{
  int i = blockIdx.x*256 + threadIdx.x;
  if (i < 4288) {
    int c = i >> 6, d = i & 63;
    wT[i] = w0[d*CIN0 + c];
  } else if (i < 8384) {
    int j = i - 4288; int c = j >> 6, d = j & 63;
    wT[i] = w1[d*64 + c];
  } else if (i < WT_TOTAL) {
    int j = i - 8384; int c = j >> 7, d = j & 127;
    wT[i] = w2[d*64 + c];
  }
}

// ================================================================ helpers
__device__ __forceinline__ float gelu_f(float x) {
  float z = fabsf(x) * 0.70710678118654752f;
  float t = __builtin_amdgcn_rcpf(fmaf(0.3275911f, z, 1.0f));
  float p = t * fmaf(t, fmaf(t, fmaf(t, fmaf(t, 1.061405429f, -1.453152027f),
                                     1.421413741f), -0.284496736f), 0.254829592f);
  float ex = __expf(-z*z);
  float er = fmaf(-p, ex, 1.0f);
  float se = __uint_as_float(__float_as_uint(er) | (__float_as_uint(x) & 0x80000000u));
  return 0.5f * x * (1.0f + se);
}
__device__ __forceinline__ float bf_lo(uint u) { return __uint_as_float(u << 16); }
__device__ __forceinline__ float bf_hi(uint u) { return __uint_as_float(u & 0xffff0000u); }
__device__ __forceinline__ uint bfpack(float a, float b) {
  uint ua = __float_as_uint(a), ub = __float_as_uint(b);
  ua = (ua + 0x7fffu + ((ua >> 16) & 1u)) >> 16;   // RNE on bit 16
  ub = (ub + 0x7fffu + ((ub >> 16) & 1u)) >> 16;
  return (ua & 0xffffu) | (ub << 16);
}

__device__ __forceinline__ void fmac64(float (&acc)[64], const float* wrow, float xc) {
  const float4* wp = (const float4*)wrow;
#pragma unroll
  for (int i = 0; i < 16; ++i) {
    float4 w = wp[i];
    acc[i*4+0] = fmaf(xc, w.x, acc[i*4+0]);
    acc[i*4+1] = fmaf(xc, w.y, acc[i*4+1]);
    acc[i*4+2] = fmaf(xc, w.z, acc[i*4+2]);
    acc[i*4+3] = fmaf(xc, w.w, acc[i*4+3]);
  }
}
__device__ __forceinline__ void fmac128(float (&acc)[128], const float* wrow, float xc) {
  const float4* wp = (const float4*)wrow;
#pragma unroll
  for (int i = 0; i < 32; ++i) {
    float4 w = wp[i];
    acc[i*4+0] = fmaf(xc, w.x, acc[i*4+0]);
    acc[i*4+1] = fmaf(xc, w.y, acc[i*4+1]);
    acc[i*4+2] = fmaf(xc, w.z, acc[i*4+2]);
    acc[i*4+3] = fmaf(xc, w.w, acc[i*4+3]);
  }
}

// layer0 for point p into acc[64] (full gathered version)
__device__ __forceinline__ void layer0(
    const float* __restrict__ xyz, const float* __restrict__ feat,
    const float* __restrict__ centers, const int* __restrict__ gidx,
    const float* wptr, const float* b0v, int p, float (&acc)[64])
{
  const int b = p >> 15;
  const int s = (p & 32767) >> 5;
  const int gi = gidx[p];
#pragma unroll
  for (int d = 0; d < 64; ++d) acc[d] = b0v[d];
  const float* cp = centers + ((size_t)(b*NS + s))*3;
  const float* pp = xyz + ((size_t)(b*NN) + gi)*3;
  const float4* fr = (const float4*)(feat + ((size_t)(b*NN) + gi)*64);
  float4 f = fr[0];
  fmac64(acc, wptr + 0*64, pp[0]-cp[0]);
  fmac64(acc, wptr + 1*64, pp[1]-cp[1]);
  fmac64(acc, wptr + 2*64, pp[2]-cp[2]);
#pragma unroll 1
  for (int q = 0; q < 16; ++q) {
    const int nq = (q < 15) ? q + 1 : 15;
    float4 fn = fr[nq];
    fmac64(acc, wptr + (3+q*4)*64, f.x);
    fmac64(acc, wptr + (4+q*4)*64, f.y);
    fmac64(acc, wptr + (5+q*4)*64, f.z);
    fmac64(acc, wptr + (6+q*4)*64, f.w);
    f = fn;
  }
}

// per-channel block column-sums of v into bsum/bssq
__device__ __forceinline__ void block_colsum64(const float (&v)[64], float* sbuf,
    float* bsum, float* bssq, int cbase)
{
  const int tid = threadIdx.x;
#pragma unroll
  for (int cc = 0; cc < 4; ++cc) {
    __syncthreads();
#pragma unroll
    for (int j = 0; j < 16; ++j) sbuf[tid*17 + j] = v[cc*16 + j];
    __syncthreads();
    const int c = tid & 15, seg = tid >> 4;
    float s = 0.f, q = 0.f;
#pragma unroll
    for (int i = 0; i < 16; ++i) {
      float x = sbuf[(seg*16 + i)*17 + c];
      s += x; q += x*x;
    }
    __syncthreads();
    sbuf[tid*2] = s; sbuf[tid*2+1] = q;
    __syncthreads();
    if (tid < 16) {
      float ss = 0.f, qq = 0.f;
#pragma unroll
      for (int sg = 0; sg < 16; ++sg) {
        ss += sbuf[(sg*16 + tid)*2];
        qq += sbuf[(sg*16 + tid)*2 + 1];
      }
      bsum[cbase + cc*16 + tid] += ss;
      bssq[cbase + cc*16 + tid] += qq;
    }
  }
  __syncthreads();
}

// ================================================================ F0 precompute
__global__ __launch_bounds__(256,3) void f0_kernel(
    const float* __restrict__ feat, const float* __restrict__ wT,
    const float* __restrict__ b0, float* __restrict__ F0)
{
  const int r = blockIdx.x*256 + threadIdx.x;
  const float* wf = wT + W0T_OFF + 3*64;
  float acc[64];
#pragma unroll
  for (int d = 0; d < 64; ++d) acc[d] = b0[d];
  const float4* fr = (const float4*)(feat + (size_t)r*64);
  float4 f = fr[0];
#pragma unroll 1
  for (int q = 0; q < 16; ++q) {
    const int nq = (q < 15) ? q + 1 : 15;
    float4 fn = fr[nq];
    fmac64(acc, wf + (q*4+0)*64, f.x);
    fmac64(acc, wf + (q*4+1)*64, f.y);
    fmac64(acc, wf + (q*4+2)*64, f.z);
    fmac64(acc, wf + (q*4+3)*64, f.w);
    f = fn;
  }
  float4* orow = (float4*)(F0 + (size_t)r*64);
#pragma unroll
  for (int q = 0; q < 16; ++q)
    orow[q] = make_float4(acc[q*4], acc[q*4+1], acc[q*4+2], acc[q*4+3]);
}

// ================================================================ tiered pipeline (r9 structure; p0 templated on F0)
template<bool WITH_F0>
__global__ __launch_bounds__(256,3) void p0_kernel(
    const float* __restrict__ xyz, const float* __restrict__ feat,
    const float* __restrict__ centers, const int* __restrict__ gidx,
    const float* __restrict__ wT, const float* __restrict__ b0,
    const float* __restrict__ F0, ushort* __restrict__ X,
    float* __restrict__ stat0)
{
  __shared__ float sbuf[4352];
  __shared__ float bsum[64], bssq[64], b0s[64];
  const int tid = threadIdx.x;
  if (tid < 64) { bsum[tid] = 0.f; bssq[tid] = 0.f; b0s[tid] = b0[tid]; }
  __syncthreads();
  const int p = blockIdx.x*256 + tid;
  float acc[64];
  if constexpr (WITH_F0) {
    const int b = p >> 15;
    const int s = (p & 32767) >> 5;
    const int gi = gidx[p];
    const float4* f0r = (const float4*)(F0 + ((size_t)(b*NN) + gi)*64);
#pragma unroll
    for (int q = 0; q < 16; ++q) {
      float4 v = f0r[q];
      acc[q*4+0] = v.x; acc[q*4+1] = v.y; acc[q*4+2] = v.z; acc[q*4+3] = v.w;
    }
    const float* cp = centers + ((size_t)(b*NS + s))*3;
    const float* pp = xyz + ((size_t)(b*NN) + gi)*3;
    fmac64(acc, wT + W0T_OFF + 0*64, pp[0]-cp[0]);
    fmac64(acc, wT + W0T_OFF + 1*64, pp[1]-cp[1]);
    fmac64(acc, wT + W0T_OFF + 2*64, pp[2]-cp[2]);
  } else {
    layer0(xyz, feat, centers, gidx, wT + W0T_OFF, b0s, p, acc);
  }
  uint4* xr = (uint4*)(X + (size_t)p*64);
#pragma unroll
  for (int q = 0; q < 8; ++q) {
    uint4 pk;
    pk.x = bfpack(acc[q*8+0], acc[q*8+1]);
    pk.y = bfpack(acc[q*8+2], acc[q*8+3]);
    pk.z = bfpack(acc[q*8+4], acc[q*8+5]);
    pk.w = bfpack(acc[q*8+6], acc[q*8+7]);
    xr[q] = pk;
  }
  block_colsum64(acc, sbuf, bsum, bssq, 0);
  if (tid < 64) {
    atomicAdd(&stat0[tid], bsum[tid]);
    atomicAdd(&stat0[64+tid], bssq[tid]);
  }
}

__global__ __launch_bounds__(256,3) void p1_kernel(
    ushort* X, const float* __restrict__ wT,
    const float* __restrict__ stat0, const float* __restrict__ g0,
    const float* __restrict__ be0, const float* __restrict__ b1,
    float* __restrict__ stat1)
{
  __shared__ float sbuf[4352];
  __shared__ float bsum[64], bssq[64];
  __shared__ float sc[64], sh[64], b1s[64];
  const float* __restrict__ w1g = wT + W1T_OFF;
  const int tid = threadIdx.x;
  if (tid < 64) {
    float m0 = stat0[tid]*INV_NPTS;
    float v0 = stat0[64+tid]*INV_NPTS - m0*m0;
    float s0 = (1.0f/sqrtf(v0 + BN_EPS)) * g0[tid];
    sc[tid] = s0; sh[tid] = be0[tid] - m0*s0;
    b1s[tid] = b1[tid];
    bsum[tid] = 0.f; bssq[tid] = 0.f;
  }
  __syncthreads();
  const int p = blockIdx.x*256 + tid;
  uint4* xr = (uint4*)(X + (size_t)p*64);
  float acc[64];
#pragma unroll
  for (int d = 0; d < 64; ++d) acc[d] = b1s[d];
  uint4 v = xr[0];
#pragma unroll 1
  for (int ch = 0; ch < 8; ++ch) {
    const int nc = (ch < 7) ? ch + 1 : 7;
    uint4 vn = xr[nc];
    const int c = ch*8;
    float x0 = gelu_f(fmaf(bf_lo(v.x), sc[c+0], sh[c+0]));
    float x1 = gelu_f(fmaf(bf_hi(v.x), sc[c+1], sh[c+1]));
    float x2 = gelu_f(fmaf(bf_lo(v.y), sc[c+2], sh[c+2]));
    float x3 = gelu_f(fmaf(bf_hi(v.y), sc[c+3], sh[c+3]));
    float x4 = gelu_f(fmaf(bf_lo(v.z), sc[c+4], sh[c+4]));
    float x5 = gelu_f(fmaf(bf_hi(v.z), sc[c+5], sh[c+5]));
    float x6 = gelu_f(fmaf(bf_lo(v.w), sc[c+6], sh[c+6]));
    float x7 = gelu_f(fmaf(bf_hi(v.w), sc[c+7], sh[c+7]));
    fmac64(acc, w1g + (c+0)*64, x0);
    fmac64(acc, w1g + (c+1)*64, x1);
    fmac64(acc, w1g + (c+2)*64, x2);
    fmac64(acc, w1g + (c+3)*64, x3);
    fmac64(acc, w1g + (c+4)*64, x4);
    fmac64(acc, w1g + (c+5)*64, x5);
    fmac64(acc, w1g + (c+6)*64, x6);
    fmac64(acc, w1g + (c+7)*64, x7);
    v = vn;
  }
#pragma unroll
  for (int q = 0; q < 8; ++q) {
    uint4 pk;
    pk.x = bfpack(acc[q*8+0], acc[q*8+1]);
    pk.y = bfpack(acc[q*8+2], acc[q*8+3]);
    pk.z = bfpack(acc[q*8+4], acc[q*8+5]);
    pk.w = bfpack(acc[q*8+6], acc[q*8+7]);
    xr[q] = pk;
  }
  block_colsum64(acc, sbuf, bsum, bssq, 0);
  if (tid < 64) {
    atomicAdd(&stat1[tid], bsum[tid]);
    atomicAdd(&stat1[64+tid], bssq[tid]);
  }
}

template<bool STORE_H2>
__global__ __launch_bounds__(256,2) void p2_kernel(
    ushort* X, ushort* __restrict__ H2, const float* __restrict__ wT,
    const float* __restrict__ stat1, const float* __restrict__ g1,
    const float* __restrict__ be1, const float* __restrict__ b2,
    float* __restrict__ stat2)
{
  __shared__ float sbuf[4352];
  __shared__ float bsum[128], bssq[128];
  __shared__ float sc[64], sh[64], b2s[128];
  const float* __restrict__ w2g = wT + W2T_OFF;
  const int tid = threadIdx.x;
  if (tid < 64) {
    float m1 = stat1[tid]*INV_NPTS;
    float v1 = stat1[64+tid]*INV_NPTS - m1*m1;
    float s1 = (1.0f/sqrtf(v1 + BN_EPS)) * g1[tid];
    sc[tid] = s1; sh[tid] = be1[tid] - m1*s1;
  }
  if (tid < 128) { b2s[tid] = b2[tid]; bsum[tid] = 0.f; bssq[tid] = 0.f; }
  __syncthreads();
  const int p = blockIdx.x*256 + tid;
  uint4* xr = (uint4*)(X + (size_t)p*64);
  float acc[128];
#pragma unroll
  for (int d = 0; d < 128; ++d) acc[d] = b2s[d];
  uint4 v = xr[0];
#pragma unroll 1
  for (int ch = 0; ch < 8; ++ch) {
    const int nc = (ch < 7) ? ch + 1 : 7;
    uint4 vn = xr[nc];
    const int c = ch*8;
    float x0 = gelu_f(fmaf(bf_lo(v.x), sc[c+0], sh[c+0]));
    float x1 = gelu_f(fmaf(bf_hi(v.x), sc[c+1], sh[c+1]));
    float x2 = gelu_f(fmaf(bf_lo(v.y), sc[c+2], sh[c+2]));
    float x3 = gelu_f(fmaf(bf_hi(v.y), sc[c+3], sh[c+3]));
    float x4 = gelu_f(fmaf(bf_lo(v.z), sc[c+4], sh[c+4]));
    float x5 = gelu_f(fmaf(bf_hi(v.z), sc[c+5], sh[c+5]));
    float x6 = gelu_f(fmaf(bf_lo(v.w), sc[c+6], sh[c+6]));
    float x7 = gelu_f(fmaf(bf_hi(v.w), sc[c+7], sh[c+7]));
    if (!STORE_H2) {
      uint4 pk;
      pk.x = bfpack(x0, x1); pk.y = bfpack(x2, x3);
      pk.z = bfpack(x4, x5); pk.w = bfpack(x6, x7);
      xr[ch] = pk;
    }
    fmac128(acc, w2g + (c+0)*128, x0);
    fmac128(acc, w2g + (c+1)*128, x1);
    fmac128(acc, w2g + (c+2)*128, x2);
    fmac128(acc, w2g + (c+3)*128, x3);
    fmac128(acc, w2g + (c+4)*128, x4);
    fmac128(acc, w2g + (c+5)*128, x5);
    fmac128(acc, w2g + (c+6)*128, x6);
    fmac128(acc, w2g + (c+7)*128, x7);
    v = vn;
  }
  if (STORE_H2) {
    uint4* hr = (uint4*)(H2 + (size_t)p*128);
#pragma unroll
    for (int q = 0; q < 16; ++q) {
      uint4 pk;
      pk.x = bfpack(acc[q*8+0], acc[q*8+1]);
      pk.y = bfpack(acc[q*8+2], acc[q*8+3]);
      pk.z = bfpack(acc[q*8+4], acc[q*8+5]);
      pk.w = bfpack(acc[q*8+6], acc[q*8+7]);
      hr[q] = pk;
    }
  }
#pragma unroll
  for (int half = 0; half < 2; ++half) {
    float tmp[64];
#pragma unroll
    for (int d = 0; d < 64; ++d) tmp[d] = acc[half*64 + d];
    block_colsum64(tmp, sbuf, bsum, bssq, half*64);
  }
  if (tid < 128) {
    atomicAdd(&stat2[tid], bsum[tid]);
    atomicAdd(&stat2[128+tid], bssq[tid]);
  }
}

__global__ __launch_bounds__(128) void fbig_kernel(
    const ushort* __restrict__ H2, const float* __restrict__ stat2,
    const float* __restrict__ g2, const float* __restrict__ be2,
    float* __restrict__ out_feat)
{
  const int d = threadIdx.x;
  const int bs = blockIdx.x;
  const float mean = stat2[d] * INV_NPTS;
  const float var  = stat2[128+d] * INV_NPTS - mean*mean;
  const float scale = (1.0f/sqrtf(var + BN_EPS)) * g2[d];
  const float shift = be2[d] - mean*scale;
  const ushort* rp = H2 + (size_t)bs*NK*128 + d;
  float m = -3.4e38f;
#pragma unroll 4
  for (int k = 0; k < NK; ++k) {
    float t = __uint_as_float(((uint)rp[k*128]) << 16);
    m = fmaxf(m, gelu_f(fmaf(t, scale, shift)));
  }
  out_feat[(size_t)bs*128 + d] = m;
}

__global__ __launch_bounds__(256,2) void fsmall_kernel(
    const ushort* __restrict__ X, const float* __restrict__ wT,
    const float* __restrict__ b2, const float* __restrict__ stat2,
    const float* __restrict__ g2, const float* __restrict__ be2,
    float* __restrict__ out_feat)
{
  __shared__ float b2s[128], sc2[128], sh2[128];
  const float* __restrict__ w2g = wT + W2T_OFF;
  const int tid = threadIdx.x;
  if (tid < 128) {
    b2s[tid] = b2[tid];
    float m2 = stat2[tid]*INV_NPTS;
    float v2 = stat2[128+tid]*INV_NPTS - m2*m2;
    float s2 = (1.0f/sqrtf(v2 + BN_EPS)) * g2[tid];
    sc2[tid] = s2; sh2[tid] = be2[tid] - m2*s2;
  }
  __syncthreads();
  const int p = blockIdx.x*256 + tid;
  const int bs = p >> 5;
  const uint4* xr = (const uint4*)(X + (size_t)p*64);
  float acc[128];
#pragma unroll
  for (int d = 0; d < 128; ++d) acc[d] = b2s[d];
  uint4 v = xr[0];
#pragma unroll 1
  for (int ch = 0; ch < 8; ++ch) {
    const int nc = (ch < 7) ? ch + 1 : 7;
    uint4 vn = xr[nc];
    const int c = ch*8;
    fmac128(acc, w2g + (c+0)*128, bf_lo(v.x));
    fmac128(acc, w2g + (c+1)*128, bf_hi(v.x));
    fmac128(acc, w2g + (c+2)*128, bf_lo(v.y));
    fmac128(acc, w2g + (c+3)*128, bf_hi(v.y));
    fmac128(acc, w2g + (c+4)*128, bf_lo(v.z));
    fmac128(acc, w2g + (c+5)*128, bf_hi(v.z));
    fmac128(acc, w2g + (c+6)*128, bf_lo(v.w));
    fmac128(acc, w2g + (c+7)*128, bf_hi(v.w));
    v = vn;
  }
#pragma unroll
  for (int d = 0; d < 128; ++d) {
    float y = gelu_f(fmaf(acc[d], sc2[d], sh2[d]));
#pragma unroll
    for (int m = 1; m < 32; m <<= 1) y = fmaxf(y, __shfl_xor(y, m));
    acc[d] = y;
  }
  if ((tid & 31) == 0) {
    float4* op = (float4*)(out_feat + (size_t)bs*128);
#pragma unroll
    for (int i = 0; i < 32; ++i)
      op[i] = make_float4(acc[i*4], acc[i*4+1], acc[i*4+2], acc[i*4+3]);
  }
}

// ================================================================ fallback (recompute path; unchanged)
__device__ __forceinline__ void chain_to_x2(
    const float* __restrict__ xyz, const float* __restrict__ feat,
    const float* __restrict__ centers, const int* __restrict__ gidx,
    const float* wsh, float* sbuf, const float* prm, int p, float (&x2)[64])
{
  float acc0[64];
  layer0(xyz, feat, centers, gidx, wsh, prm, p, acc0);
#pragma unroll
  for (int c = 0; c < 64; ++c) acc0[c] = gelu_f(fmaf(acc0[c], prm[64+c], prm[128+c]));
#pragma unroll
  for (int d = 0; d < 64; ++d) x2[d] = prm[192+d];
  float* xrow = sbuf + threadIdx.x*17;
#pragma unroll
  for (int cc = 0; cc < 4; ++cc) {
#pragma unroll
    for (int j = 0; j < 16; ++j) xrow[j] = acc0[cc*16 + j];
#pragma unroll 1
    for (int cj = 0; cj < 16; ++cj)
      fmac64(x2, wsh + W1T_OFF + (cc*16+cj)*64, xrow[cj]);
  }
#pragma unroll
  for (int c = 0; c < 64; ++c) x2[c] = gelu_f(fmaf(x2[c], prm[256+c], prm[320+c]));
}

__global__ __launch_bounds__(256,2) void s0_kernel(
    const float* __restrict__ xyz, const float* __restrict__ feat,
    const float* __restrict__ centers, const int* __restrict__ gidx,
    const float* __restrict__ wT, const float* __restrict__ b0,
    float* __restrict__ stat0)
{
  __shared__ float wsh[4288];
  __shared__ float sbuf[4352];
  __shared__ float bsum[64], bssq[64], b0s[64];
  const int tid = threadIdx.x;
  for (int i = tid; i < 1072; i += 256) ((float4*)wsh)[i] = ((const float4*)wT)[i];
  if (tid < 64) { bsum[tid] = 0.f; bssq[tid] = 0.f; b0s[tid] = b0[tid]; }
  __syncthreads();
  const int p = blockIdx.x*256 + tid;
  float acc[64];
  layer0(xyz, feat, centers, gidx, wsh, b0s, p, acc);
  block_colsum64(acc, sbuf, bsum, bssq, 0);
  if (tid < 64) {
    atomicAdd(&stat0[tid], bsum[tid]);
    atomicAdd(&stat0[64+tid], bssq[tid]);
  }
}

__global__ __launch_bounds__(256,2) void s1_kernel(
    const float* __restrict__ xyz, const float* __restrict__ feat,
    const float* __restrict__ centers, const int* __restrict__ gidx,
    const float* __restrict__ wT, const float* __restrict__ stat0,
    const float* __restrict__ g0, const float* __restrict__ be0,
    const float* __restrict__ b0, const float* __restrict__ b1,
    float* __restrict__ stat1)
{
  __shared__ float wsh[8384];
  __shared__ float sbuf[4352];
  __shared__ float bsum[64], bssq[64];
  __shared__ float prm[256];
  const int tid = threadIdx.x;
  for (int i = tid; i < 2096; i += 256) ((float4*)wsh)[i] = ((const float4*)wT)[i];
  if (tid < 64) {
    float m0 = stat0[tid]*INV_NPTS;
    float v0 = stat0[64+tid]*INV_NPTS - m0*m0;
    float sc0 = (1.0f/sqrtf(v0 + BN_EPS)) * g0[tid];
    prm[tid] = b0[tid]; prm[64+tid] = sc0; prm[128+tid] = be0[tid] - m0*sc0;
    prm[192+tid] = b1[tid];
    bsum[tid] = 0.f; bssq[tid] = 0.f;
  }
  __syncthreads();
  const int p = blockIdx.x*256 + tid;
  float acc0[64];
  layer0(xyz, feat, centers, gidx, wsh, prm, p, acc0);
#pragma unroll
  for (int c = 0; c < 64; ++c) acc0[c] = gelu_f(fmaf(acc0[c], prm[64+c], prm[128+c]));
  float acc1[64];
#pragma unroll
  for (int d = 0; d < 64; ++d) acc1[d] = prm[192+d];
  float* xrow = sbuf + tid*17;
#pragma unroll
  for (int cc = 0; cc < 4; ++cc) {
#pragma unroll
    for (int j = 0; j < 16; ++j) xrow[j] = acc0[cc*16 + j];
#pragma unroll 1
    for (int cj = 0; cj < 16; ++cj)
      fmac64(acc1, wsh + W1T_OFF + (cc*16+cj)*64, xrow[cj]);
  }
  block_colsum64(acc1, sbuf, bsum, bssq, 0);
  if (tid < 64) {
    atomicAdd(&stat1[tid], bsum[tid]);
    atomicAdd(&stat1[64+tid], bssq[tid]);
  }
}

__global__ __launch_bounds__(256,2) void s2_kernel(
    const float* __restrict__ xyz, const float* __restrict__ feat,
    const float* __restrict__ centers, const int* __restrict__ gidx,
    const float* __restrict__ wT,
    const float* __restrict__ stat0, const float* __restrict__ g0,
    const float* __restrict__ be0, const float* __restrict__ b0,
    const float* __restrict__ b1, const float* __restrict__ stat1,
    const float* __restrict__ g1, const float* __restrict__ be1,
    const float* __restrict__ b2, float* __restrict__ stat2)
{
  __shared__ float wsh[8384];
  __shared__ float sbuf[4352];
  __shared__ float bsum[128], bssq[128];
  __shared__ float prm[512];
  const int tid = threadIdx.x;
  for (int i = tid; i < 2096; i += 256) ((float4*)wsh)[i] = ((const float4*)wT)[i];
  if (tid < 64) {
    float m0 = stat0[tid]*INV_NPTS;
    float v0 = stat0[64+tid]*INV_NPTS - m0*m0;
    float sc0 = (1.0f/sqrtf(v0 + BN_EPS)) * g0[tid];
    prm[tid] = b0[tid]; prm[64+tid] = sc0; prm[128+tid] = be0[tid] - m0*sc0;
    float m1 = stat1[tid]*INV_NPTS;
    float v1 = stat1[64+tid]*INV_NPTS - m1*m1;
    float sc1 = (1.0f/sqrtf(v1 + BN_EPS)) * g1[tid];
    prm[192+tid] = b1[tid]; prm[256+tid] = sc1; prm[320+tid] = be1[tid] - m1*sc1;
  }
  if (tid < 128) { prm[384+tid] = b2[tid]; bsum[tid] = 0.f; bssq[tid] = 0.f; }
  __syncthreads();
  const int p = blockIdx.x*256 + tid;
  float x2[64];
  chain_to_x2(xyz, feat, centers, gidx, wsh, sbuf, prm, p, x2);
  __syncthreads();
  for (int i = tid; i < 2048; i += 256)
    ((float4*)wsh)[i] = ((const float4*)(wT + W2T_OFF))[i];
  __syncthreads();
  float* xrow = sbuf + tid*17;
#pragma unroll 1
  for (int half = 0; half < 2; ++half) {
    float a2[64];
#pragma unroll
    for (int d = 0; d < 64; ++d) a2[d] = prm[384 + half*64 + d];
#pragma unroll
    for (int cc = 0; cc < 4; ++cc) {
#pragma unroll
      for (int j = 0; j < 16; ++j) xrow[j] = x2[cc*16 + j];
#pragma unroll 1
      for (int cj = 0; cj < 16; ++cj)
        fmac64(a2, wsh + (cc*16+cj)*128 + half*64, xrow[cj]);
    }
    block_colsum64(a2, sbuf, bsum, bssq, half*64);
  }
  if (tid < 128) {
    atomicAdd(&stat2[tid], bsum[tid]);
    atomicAdd(&stat2[128+tid], bssq[tid]);
  }
}

__global__ __launch_bounds__(256,2) void fin_kernel(
    const float* __restrict__ xyz, const float* __restrict__ feat,
    const float* __restrict__ centers, const int* __restrict__ gidx,
    const float* __restrict__ wT,
    const float* __restrict__ stat0, const float* __restrict__ g0,
    const float* __restrict__ be0, const float* __restrict__ b0,
    const float* __restrict__ b1, const float* __restrict__ stat1,
    const float* __restrict__ g1, const float* __restrict__ be1,
    const float* __restrict__ b2, const float* __restrict__ stat2,
    const float* __restrict__ g2, const float* __restrict__ be2,
    float* __restrict__ out_feat)
{
  __shared__ float wsh[8384];
  __shared__ float sbuf[4352];
  __shared__ float prm[768];
  const int tid = threadIdx.x;
  for (int i = tid; i < 2096; i += 256) ((float4*)wsh)[i] = ((const float4*)wT)[i];
  if (tid < 64) {
    float m0 = stat0[tid]*INV_NPTS;
    float v0 = stat0[64+tid]*INV_NPTS - m0*m0;
    float sc0 = (1.0f/sqrtf(v0 + BN_EPS)) * g0[tid];
    prm[tid] = b0[tid]; prm[64+tid] = sc0; prm[128+tid] = be0[tid] - m0*sc0;
    float m1 = stat1[tid]*INV_NPTS;
    float v1 = stat1[64+tid]*INV_NPTS - m1*m1;
    float sc1 = (1.0f/sqrtf(v1 + BN_EPS)) * g1[tid];
    prm[192+tid] = b1[tid]; prm[256+tid] = sc1; prm[320+tid] = be1[tid] - m1*sc1;
  }
  if (tid < 128) {
    prm[384+tid] = b2[tid];
    float m2 = stat2[tid]*INV_NPTS;
    float v2 = stat2[128+tid]*INV_NPTS - m2*m2;
    float sc2 = (1.0f/sqrtf(v2 + BN_EPS)) * g2[tid];
    prm[512+tid] = sc2; prm[640+tid] = be2[tid] - m2*sc2;
  }
  __syncthreads();
  const int p = blockIdx.x*256 + tid;
  const int b = p >> 15;
  const int s = (p & 32767) >> 5;
  float x2[64];
  chain_to_x2(xyz, feat, centers, gidx, wsh, sbuf, prm, p, x2);
  __syncthreads();
  for (int i = tid; i < 2048; i += 256)
    ((float4*)wsh)[i] = ((const float4*)(wT + W2T_OFF))[i];
  __syncthreads();
  float* xrow = sbuf + tid*17;
#pragma unroll 1
  for (int half = 0; half < 2; ++half) {
    float a2[64];
#pragma unroll
    for (int d = 0; d < 64; ++d) a2[d] = prm[384 + half*64 + d];
#pragma unroll
    for (int cc = 0; cc < 4; ++cc) {
#pragma unroll
      for (int j = 0; j < 16; ++j) xrow[j] = x2[cc*16 + j];
#pragma unroll 1
      for (int cj = 0; cj < 16; ++cj)
        fmac64(a2, wsh + (cc*16+cj)*128 + half*64, xrow[cj]);
    }
#pragma unroll
    for (int d = 0; d < 64; ++d) {
      float y = gelu_f(fmaf(a2[d], prm[512 + half*64 + d], prm[640 + half*64 + d]));
#pragma unroll
      for (int m = 1; m < 32; m <<= 1) y = fmaxf(y, __shfl_xor(y, m));
      a2[d] = y;
    }
    if ((tid & 31) == 0) {
      float4* op = (float4*)(out_feat + ((size_t)(b*NS + s))*128 + half*64);
#pragma unroll
      for (int i = 0; i < 16; ++i)
        op[i] = make_float4(a2[i*4], a2[i*4+1], a2[i*4+2], a2[i*4+3]);
    }
  }
}

// ================================================================ launch
extern "C" void kernel_launch(void* const* d_in, const int* in_sizes, int n_in,
                              void* d_out, int out_size, void* d_ws, size_t ws_size,
                              hipStream_t stream) {
  (void)in_sizes; (void)n_in; (void)out_size;
  const float* xyz      = (const float*)d_in[0];
  const float* features = (const float*)d_in[1];
  const float* w0  = (const float*)d_in[2];
  const float* b0  = (const float*)d_in[3];
  const float* g0  = (const float*)d_in[4];
  const float* be0 = (const float*)d_in[5];
  const float* w1  = (const float*)d_in[6];
  const float* b1  = (const float*)d_in[7];
  const float* g1  = (const float*)d_in[8];
  const float* be1 = (const float*)d_in[9];
  const float* w2  = (const float*)d_in[10];
  const float* b2  = (const float*)d_in[11];
  const float* g2  = (const float*)d_in[12];
  const float* be2 = (const float*)d_in[13];

  float* out = (float*)d_out;
  float* out_newxyz = out;                 // (16,1024,3)
  float* out_feat   = out + NB*NS*3;       // (16,1024,128)

  char* ws = (char*)d_ws;
  size_t off = 0;
  float* centers   = (float*)(ws + off); off += (size_t)NB*NS*3*4;
  int*   group_idx = (int*)(ws + off);   off += (size_t)NPTS*4;
  float* stats     = (float*)(ws + off); off += 512*4;
  off = (off + 255) & ~(size_t)255;
  float* wT        = (float*)(ws + off); off += (size_t)WT_TOTAL*4;
  off = (off + 255) & ~(size_t)255;
  const size_t base_end = off;
  const size_t X_bytes  = (size_t)NPTS*64*2;    // 67.1 MB
  const size_t H2_bytes = (size_t)NPTS*128*2;   // 134.2 MB
  const size_t F0_bytes = (size_t)NROWS*64*4;   // 16.8 MB
  ushort* X  = (ushort*)(ws + base_end);
  ushort* H2 = (ushort*)(ws + base_end + X_bytes);

  // Tier thresholds unchanged; F0 appended after the active tier's buffers.
  const bool tier_big   = ws_size >= base_end + X_bytes + H2_bytes;
  const bool tier_small = !tier_big && ws_size >= base_end + X_bytes;
  if (ws_size < base_end) return;
  const size_t f0_off = tier_big ? base_end + X_bytes + H2_bytes
                                 : base_end + X_bytes;
  const bool use_f0 = (tier_big || tier_small) && (ws_size >= f0_off + F0_bytes);
  float* F0 = (float*)(ws + f0_off);

  float* stat0 = stats;
  float* stat1 = stats + 128;
  float* stat2 = stats + 256;

  (void)hipMemsetAsync(stats, 0, 2048, stream);
  prep_kernel<<<65, 256, 0, stream>>>(w0, w1, w2, wT);
  if (use_f0)
    f0_kernel<<<NROWS/256, 256, 0, stream>>>(features, wT, b0, F0);
  fps_kernel<<<NB, FPS_T, 0, stream>>>(xyz, centers, out_newxyz);
  ball_kernel<<<NB*64, 256, 0, stream>>>(xyz, centers, group_idx);

  if (tier_big || tier_small) {
    if (use_f0)
      p0_kernel<true><<<NPTS/256, 256, 0, stream>>>(xyz, features, centers, group_idx,
                                                    wT, b0, F0, X, stat0);
    else
      p0_kernel<false><<<NPTS/256, 256, 0, stream>>>(xyz, features, centers, group_idx,
                                                     wT, b0, F0, X, stat0);
    p1_kernel<<<NPTS/256, 256, 0, stream>>>(X, wT, stat0, g0, be0, b1, stat1);
    if (tier_big) {
      p2_kernel<true><<<NPTS/256, 256, 0, stream>>>(X, H2, wT, stat1, g1, be1, b2, stat2);
      fbig_kernel<<<NB*NS, 128, 0, stream>>>(H2, stat2, g2, be2, out_feat);
    } else {
      p2_kernel<false><<<NPTS/256, 256, 0, stream>>>(X, H2, wT, stat1, g1, be1, b2, stat2);
      fsmall_kernel<<<NPTS/256, 256, 0, stream>>>(X, wT, b2, stat2, g2, be2, out_feat);
    }
  } else {
    s0_kernel<<<NPTS/256, 256, 0, stream>>>(xyz, features, centers, group_idx, wT, b0, stat0);
    s1_kernel<<<NPTS/256, 256, 0, stream>>>(xyz, features, centers, group_idx, wT,
                                            stat0, g0, be0, b0, b1, stat1);
    s2_kernel<<<NPTS/256, 256, 0, stream>>>(xyz, features, centers, group_idx, wT,
                                            stat0, g0, be0, b0, b1, stat1, g1, be1, b2, stat2);
    fin_kernel<<<NPTS/256, 256, 0, stream>>>(xyz, features, centers, group_idx, wT,
                                             stat0, g0, be0, b0, b1, stat1, g1, be1, b2,
                                             stat2, g2, be2, out_feat);
  }
}

// Round 13
// 1360.706 us; speedup vs baseline: 1.8016x; 1.8016x over previous
//
#include <hip/hip_runtime.h>

typedef unsigned int uint;
typedef unsigned short ushort;
typedef unsigned long long ull;

#define NB 16
#define NN 4096
#define NS 1024
#define NK 32
#define CIN0 67
#define NPTS (NB*NS*NK)           // 524288
#define NROWS (NB*NN)             // 65536 source rows
#define BN_EPS 1e-5f
#define INV_NPTS (1.0f/524288.0f) // exact power of two

// transposed-weight offsets inside wT (floats)
#define W0T_OFF 0      // [67][64]  = 4288
#define W1T_OFF 4288   // [64][64]  = 4096
#define W2T_OFF 8384   // [64][128] = 8192
#define WT_TOTAL 16576

// ================================================================ FPS v6 (r9/r11-validated: 832us, VGPR 88, no spill)
#define FPS_T 256
#define PPT (NN / FPS_T) // 16

// dpp_ctrl: row_ror:N = 0x120+N ; row_bcast15 = 0x142 ; row_bcast31 = 0x143
#define KMAX_STEP(K, CTRL) do { \
    uint _lo = (uint)(K), _hi = (uint)((K) >> 32); \
    uint _nlo = (uint)__builtin_amdgcn_update_dpp(0, (int)_lo, (CTRL), 0xF, 0xF, true); \
    uint _nhi = (uint)__builtin_amdgcn_update_dpp(0, (int)_hi, (CTRL), 0xF, 0xF, true); \
    ull _nk = ((ull)_nhi << 32) | _nlo; \
    if (_nk > (K)) (K) = _nk; \
  } while (0)

// merge 4 wave entries (keys + attached coords); no dependent LDS read after.
__device__ __forceinline__ void fps_block_merge(
    const uint2* sk, const float4* sc,
    float& cx, float& cy, float& cz, int& fi)
{
  uint4 e01 = *(const uint4*)&sk[0];
  uint4 e23 = *(const uint4*)&sk[2];
  ull k0 = ((ull)e01.y << 32) | e01.x;
  ull k1 = ((ull)e01.w << 32) | e01.z;
  ull k2 = ((ull)e23.y << 32) | e23.x;
  ull k3 = ((ull)e23.w << 32) | e23.z;
  float4 c0 = sc[0], c1 = sc[1], c2 = sc[2], c3 = sc[3];
  ull b = k0; float4 C = c0;
  if (k1 > b) { b = k1; C = c1; }
  if (k2 > b) { b = k2; C = c2; }
  if (k3 > b) { b = k3; C = c3; }
  cx = C.x; cy = C.y; cz = C.z;
  fi = (int)(~(uint)b);
}

__global__ __launch_bounds__(FPS_T) void fps_kernel(
    const float* __restrict__ xyz, float* __restrict__ centers,
    float* __restrict__ out_newxyz)
{
#pragma clang fp contract(off)
  __shared__ float4 sxyz[NN];                    // 64 KB
  __shared__ int sfar[NS];
  __shared__ __align__(16) uint2  sk[2][FPS_T/64];
  __shared__ __align__(16) float4 sc[2][FPS_T/64];
  const int b = blockIdx.x;
  const int tid = threadIdx.x;
  const int lane = tid & 63;
  const int wv = tid >> 6;
  const float* xb = xyz + (size_t)b * NN * 3;
  for (int i = tid; i < NN; i += FPS_T)
    sxyz[i] = make_float4(xb[i*3+0], xb[i*3+1], xb[i*3+2], 0.f);
  __syncthreads();
  float px[PPT], py[PPT], pz[PPT], dist[PPT];
  const int base = tid * PPT;
#pragma unroll
  for (int j = 0; j < PPT; ++j) {
    float4 P = sxyz[base+j];
    px[j] = P.x; py[j] = P.y; pz[j] = P.z;
    dist[j] = 1e10f;
  }
  float4 C0 = sxyz[0];
  float cx = C0.x, cy = C0.y, cz = C0.z;
  if (tid == 0) sfar[0] = 0;

  for (int it = 1; it < NS; ++it) {
#pragma unroll
    for (int j = 0; j < PPT; ++j) {
      float dx = px[j]-cx, dy = py[j]-cy, dz = pz[j]-cz;
      float d = (dx*dx + dy*dy) + dz*dz;
      float dd = dist[j];
      dist[j] = d < dd ? d : dd;
    }
    // local argmax tree (left operand lower index -> strict >)
    float v8[8]; int i8[8];
#pragma unroll
    for (int j = 0; j < 8; ++j) {
      bool t = dist[2*j+1] > dist[2*j];
      v8[j] = t ? dist[2*j+1] : dist[2*j];
      i8[j] = base + (t ? 2*j+1 : 2*j);
    }
    float v4[4]; int i4[4];
#pragma unroll
    for (int j = 0; j < 4; ++j) {
      bool t = v8[2*j+1] > v8[2*j];
      v4[j] = t ? v8[2*j+1] : v8[2*j];
      i4[j] = t ? i8[2*j+1] : i8[2*j];
    }
    float v2[2]; int i2[2];
#pragma unroll
    for (int j = 0; j < 2; ++j) {
      bool t = v4[2*j+1] > v4[2*j];
      v2[j] = t ? v4[2*j+1] : v4[2*j];
      i2[j] = t ? i4[2*j+1] : i4[2*j];
    }
    bool t0 = v2[1] > v2[0];
    float bv = t0 ? v2[1] : v2[0];
    int   bi = t0 ? i2[1] : i2[0];
    ull key = ((ull)__float_as_uint(bv) << 32) | (uint)(~bi);
    KMAX_STEP(key, 0x121);
    KMAX_STEP(key, 0x122);
    KMAX_STEP(key, 0x124);
    KMAX_STEP(key, 0x128);
    KMAX_STEP(key, 0x142);
    KMAX_STEP(key, 0x143);
    const int pb = it & 1;
    if (lane == 63) {
      int iw = (int)(~(uint)key);
      float4 CW = sxyz[iw];               // pre-barrier: off the merge tail
      sk[pb][wv] = make_uint2((uint)key, (uint)(key >> 32));
      sc[pb][wv] = CW;
    }
    __syncthreads();
    int fi;
    fps_block_merge(sk[pb], sc[pb], cx, cy, cz, fi);
    if (tid == 0) sfar[it] = fi;
  }
  __syncthreads();
  for (int s = tid; s < NS; s += FPS_T) {
    int f = sfar[s];
    float4 C = sxyz[f];
    size_t o = ((size_t)b * NS + s) * 3;
    centers[o] = C.x; centers[o+1] = C.y; centers[o+2] = C.z;
    out_newxyz[o] = C.x; out_newxyz[o+1] = C.y; out_newxyz[o+2] = C.z;
  }
}

// ================================================================ ball query v2 (validated r6)
#define BPAD(i) ((i) + ((i)>>6))
__global__ __launch_bounds__(256,2) void ball_kernel(
    const float* __restrict__ xyz, const float* __restrict__ centers,
    int* __restrict__ group_idx)
{
#pragma clang fp contract(off)
  __shared__ float sx[4160], sy[4160], sz[4160], sq[4160];  // 65 KB
  const int bid = blockIdx.x;            // 1024 blocks: 64 per batch
  const int b = bid >> 6;
  const int c0 = (bid & 63) << 4;        // 16 centers per block
  const int tid = threadIdx.x;
  const int lane = tid & 63;
  const int wave = tid >> 6;
  const float* xb = xyz + (size_t)b * NN * 3;
  for (int i = tid; i < NN; i += 256) {
    float x = xb[i*3+0], y = xb[i*3+1], z = xb[i*3+2];
    int a = BPAD(i);
    sx[a] = x; sy[a] = y; sz[a] = z;
    sq[a] = (x*x + y*y) + z*z;
  }
  __syncthreads();
  const int a0 = lane * 65;              // BPAD(lane*64)
#pragma unroll 1
  for (int r = 0; r < 4; ++r) {
    const int s = c0 + wave*4 + r;
    const size_t co = ((size_t)b * NS + s) * 3;
    const float cx = centers[co], cy = centers[co+1], cz = centers[co+2];
    const float csq = (cx*cx + cy*cy) + cz*cz;
    unsigned long long mask = 0ull;
#pragma unroll 8
    for (int j = 0; j < 64; ++j) {
      const float dot = (cx*sx[a0+j] + cy*sy[a0+j]) + cz*sz[a0+j];
      const float dist = (csq + sq[a0+j]) - 2.0f*dot;
      mask |= ((unsigned long long)(dist <= 0.25f)) << j;
    }
    int cnt = __popcll(mask);
    int inc = cnt;
#pragma unroll
    for (int m = 1; m < 64; m <<= 1) {
      int o = __shfl_up(inc, m);
      if (lane >= m) inc += o;
    }
    const int pre = inc - cnt;
    const int total = __shfl(inc, 63);
    unsigned long long bal = __ballot(cnt > 0);
    int fl = __ffsll(bal) - 1;
    int myfirst = cnt ? (lane << 6) + __ffsll(mask) - 1 : 0;
    int firstG = __shfl(myfirst, fl);
    int* out = group_idx + ((size_t)b * NS + s) * NK;
    if (pre < NK && cnt) {
      int k = pre;
      unsigned long long m2 = mask;
      while (m2 && k < NK) {
        int j = __ffsll(m2) - 1;
        out[k++] = (lane << 6) + j;
        m2 &= m2 - 1;
      }
    }
    if (total < NK) {
      for (int q2 = total + lane; q2 < NK; q2 += 64) out[q2] = firstG;
    }
  }
}

// ================================================================ prep
__global__ __launch_bounds__(256) void prep_kernel(
    const float* __restrict__ w0, const float* __restrict__ w1,
    const float* __restrict__ w2, float* __restrict__ wT)
{
  int i = blockIdx.x*256 + threadIdx.x;
  if (i < 4288) {
    int c = i >> 6, d = i & 63;
    wT[i] = w0[d*CIN0 + c];
  } else if (i < 8384) {
    int j = i - 4288; int c = j >> 6, d = j & 63;
    wT[i] = w1[d*64 + c];
  } else if (i < WT_TOTAL) {
    int j = i - 8384; int c = j >> 7, d = j & 127;
    wT[i] = w2[d*64 + c];
  }
}

// ================================================================ helpers
__device__ __forceinline__ float gelu_f(float x) {
  float z = fabsf(x) * 0.70710678118654752f;
  float t = __builtin_amdgcn_rcpf(fmaf(0.3275911f, z, 1.0f));
  float p = t * fmaf(t, fmaf(t, fmaf(t, fmaf(t, 1.061405429f, -1.453152027f),
                                     1.421413741f), -0.284496736f), 0.254829592f);
  float ex = __expf(-z*z);
  float er = fmaf(-p, ex, 1.0f);
  float se = __uint_as_float(__float_as_uint(er) | (__float_as_uint(x) & 0x80000000u));
  return 0.5f * x * (1.0f + se);
}
__device__ __forceinline__ float bf_lo(uint u) { return __uint_as_float(u << 16); }
__device__ __forceinline__ float bf_hi(uint u) { return __uint_as_float(u & 0xffff0000u); }
__device__ __forceinline__ uint bfpack(float a, float b) {
  uint ua = __float_as_uint(a), ub = __float_as_uint(b);
  ua = (ua + 0x7fffu + ((ua >> 16) & 1u)) >> 16;   // RNE on bit 16
  ub = (ub + 0x7fffu + ((ub >> 16) & 1u)) >> 16;
  return (ua & 0xffffu) | (ub << 16);
}

__device__ __forceinline__ void fmac64(float (&acc)[64], const float* wrow, float xc) {
  const float4* wp = (const float4*)wrow;
#pragma unroll
  for (int i = 0; i < 16; ++i) {
    float4 w = wp[i];
    acc[i*4+0] = fmaf(xc, w.x, acc[i*4+0]);
    acc[i*4+1] = fmaf(xc, w.y, acc[i*4+1]);
    acc[i*4+2] = fmaf(xc, w.z, acc[i*4+2]);
    acc[i*4+3] = fmaf(xc, w.w, acc[i*4+3]);
  }
}
__device__ __forceinline__ void fmac128(float (&acc)[128], const float* wrow, float xc) {
  const float4* wp = (const float4*)wrow;
#pragma unroll
  for (int i = 0; i < 32; ++i) {
    float4 w = wp[i];
    acc[i*4+0] = fmaf(xc, w.x, acc[i*4+0]);
    acc[i*4+1] = fmaf(xc, w.y, acc[i*4+1]);
    acc[i*4+2] = fmaf(xc, w.z, acc[i*4+2]);
    acc[i*4+3] = fmaf(xc, w.w, acc[i*4+3]);
  }
}

// layer0 for point p into acc[64] (full gathered version)
__device__ __forceinline__ void layer0(
    const float* __restrict__ xyz, const float* __restrict__ feat,
    const float* __restrict__ centers, const int* __restrict__ gidx,
    const float* wptr, const float* b0v, int p, float (&acc)[64])
{
  const int b = p >> 15;
  const int s = (p & 32767) >> 5;
  const int gi = gidx[p];
#pragma unroll
  for (int d = 0; d < 64; ++d) acc[d] = b0v[d];
  const float* cp = centers + ((size_t)(b*NS + s))*3;
  const float* pp = xyz + ((size_t)(b*NN) + gi)*3;
  const float4* fr = (const float4*)(feat + ((size_t)(b*NN) + gi)*64);
  float4 f = fr[0];
  fmac64(acc, wptr + 0*64, pp[0]-cp[0]);
  fmac64(acc, wptr + 1*64, pp[1]-cp[1]);
  fmac64(acc, wptr + 2*64, pp[2]-cp[2]);
#pragma unroll 1
  for (int q = 0; q < 16; ++q) {
    const int nq = (q < 15) ? q + 1 : 15;
    float4 fn = fr[nq];
    fmac64(acc, wptr + (3+q*4)*64, f.x);
    fmac64(acc, wptr + (4+q*4)*64, f.y);
    fmac64(acc, wptr + (5+q*4)*64, f.z);
    fmac64(acc, wptr + (6+q*4)*64, f.w);
    f = fn;
  }
}

// per-channel block column-sums of v into bsum/bssq
__device__ __forceinline__ void block_colsum64(const float (&v)[64], float* sbuf,
    float* bsum, float* bssq, int cbase)
{
  const int tid = threadIdx.x;
#pragma unroll
  for (int cc = 0; cc < 4; ++cc) {
    __syncthreads();
#pragma unroll
    for (int j = 0; j < 16; ++j) sbuf[tid*17 + j] = v[cc*16 + j];
    __syncthreads();
    const int c = tid & 15, seg = tid >> 4;
    float s = 0.f, q = 0.f;
#pragma unroll
    for (int i = 0; i < 16; ++i) {
      float x = sbuf[(seg*16 + i)*17 + c];
      s += x; q += x*x;
    }
    __syncthreads();
    sbuf[tid*2] = s; sbuf[tid*2+1] = q;
    __syncthreads();
    if (tid < 16) {
      float ss = 0.f, qq = 0.f;
#pragma unroll
      for (int sg = 0; sg < 16; ++sg) {
        ss += sbuf[(sg*16 + tid)*2];
        qq += sbuf[(sg*16 + tid)*2 + 1];
      }
      bsum[cbase + cc*16 + tid] += ss;
      bssq[cbase + cc*16 + tid] += qq;
    }
  }
  __syncthreads();
}

// ================================================================ F0 precompute
__global__ __launch_bounds__(256,3) void f0_kernel(
    const float* __restrict__ feat, const float* __restrict__ wT,
    const float* __restrict__ b0, float* __restrict__ F0)
{
  const int r = blockIdx.x*256 + threadIdx.x;
  const float* wf = wT + W0T_OFF + 3*64;
  float acc[64];
#pragma unroll
  for (int d = 0; d < 64; ++d) acc[d] = b0[d];
  const float4* fr = (const float4*)(feat + (size_t)r*64);
  float4 f = fr[0];
#pragma unroll 1
  for (int q = 0; q < 16; ++q) {
    const int nq = (q < 15) ? q + 1 : 15;
    float4 fn = fr[nq];
    fmac64(acc, wf + (q*4+0)*64, f.x);
    fmac64(acc, wf + (q*4+1)*64, f.y);
    fmac64(acc, wf + (q*4+2)*64, f.z);
    fmac64(acc, wf + (q*4+3)*64, f.w);
    f = fn;
  }
  float4* orow = (float4*)(F0 + (size_t)r*64);
#pragma unroll
  for (int q = 0; q < 16; ++q)
    orow[q] = make_float4(acc[q*4], acc[q*4+1], acc[q*4+2], acc[q*4+3]);
}

// ================================================================ tiered pipeline (r9 structure; p0 templated on F0)
template<bool WITH_F0>
__global__ __launch_bounds__(256,3) void p0_kernel(
    const float* __restrict__ xyz, const float* __restrict__ feat,
    const float* __restrict__ centers, const int* __restrict__ gidx,
    const float* __restrict__ wT, const float* __restrict__ b0,
    const float* __restrict__ F0, ushort* __restrict__ X,
    float* __restrict__ stat0)
{
  __shared__ float sbuf[4352];
  __shared__ float bsum[64], bssq[64], b0s[64];
  const int tid = threadIdx.x;
  if (tid < 64) { bsum[tid] = 0.f; bssq[tid] = 0.f; b0s[tid] = b0[tid]; }
  __syncthreads();
  const int p = blockIdx.x*256 + tid;
  float acc[64];
  if constexpr (WITH_F0) {
    const int b = p >> 15;
    const int s = (p & 32767) >> 5;
    const int gi = gidx[p];
    const float4* f0r = (const float4*)(F0 + ((size_t)(b*NN) + gi)*64);
#pragma unroll
    for (int q = 0; q < 16; ++q) {
      float4 v = f0r[q];
      acc[q*4+0] = v.x; acc[q*4+1] = v.y; acc[q*4+2] = v.z; acc[q*4+3] = v.w;
    }
    const float* cp = centers + ((size_t)(b*NS + s))*3;
    const float* pp = xyz + ((size_t)(b*NN) + gi)*3;
    fmac64(acc, wT + W0T_OFF + 0*64, pp[0]-cp[0]);
    fmac64(acc, wT + W0T_OFF + 1*64, pp[1]-cp[1]);
    fmac64(acc, wT + W0T_OFF + 2*64, pp[2]-cp[2]);
  } else {
    layer0(xyz, feat, centers, gidx, wT + W0T_OFF, b0s, p, acc);
  }
  uint4* xr = (uint4*)(X + (size_t)p*64);
#pragma unroll
  for (int q = 0; q < 8; ++q) {
    uint4 pk;
    pk.x = bfpack(acc[q*8+0], acc[q*8+1]);
    pk.y = bfpack(acc[q*8+2], acc[q*8+3]);
    pk.z = bfpack(acc[q*8+4], acc[q*8+5]);
    pk.w = bfpack(acc[q*8+6], acc[q*8+7]);
    xr[q] = pk;
  }
  block_colsum64(acc, sbuf, bsum, bssq, 0);
  if (tid < 64) {
    atomicAdd(&stat0[tid], bsum[tid]);
    atomicAdd(&stat0[64+tid], bssq[tid]);
  }
}

__global__ __launch_bounds__(256,3) void p1_kernel(
    ushort* X, const float* __restrict__ wT,
    const float* __restrict__ stat0, const float* __restrict__ g0,
    const float* __restrict__ be0, const float* __restrict__ b1,
    float* __restrict__ stat1)
{
  __shared__ float sbuf[4352];
  __shared__ float bsum[64], bssq[64];
  __shared__ float sc[64], sh[64], b1s[64];
  const float* __restrict__ w1g = wT + W1T_OFF;
  const int tid = threadIdx.x;
  if (tid < 64) {
    float m0 = stat0[tid]*INV_NPTS;
    float v0 = stat0[64+tid]*INV_NPTS - m0*m0;
    float s0 = (1.0f/sqrtf(v0 + BN_EPS)) * g0[tid];
    sc[tid] = s0; sh[tid] = be0[tid] - m0*s0;
    b1s[tid] = b1[tid];
    bsum[tid] = 0.f; bssq[tid] = 0.f;
  }
  __syncthreads();
  const int p = blockIdx.x*256 + tid;
  uint4* xr = (uint4*)(X + (size_t)p*64);
  float acc[64];
#pragma unroll
  for (int d = 0; d < 64; ++d) acc[d] = b1s[d];
  uint4 v = xr[0];
#pragma unroll 1
  for (int ch = 0; ch < 8; ++ch) {
    const int nc = (ch < 7) ? ch + 1 : 7;
    uint4 vn = xr[nc];
    const int c = ch*8;
    float x0 = gelu_f(fmaf(bf_lo(v.x), sc[c+0], sh[c+0]));
    float x1 = gelu_f(fmaf(bf_hi(v.x), sc[c+1], sh[c+1]));
    float x2 = gelu_f(fmaf(bf_lo(v.y), sc[c+2], sh[c+2]));
    float x3 = gelu_f(fmaf(bf_hi(v.y), sc[c+3], sh[c+3]));
    float x4 = gelu_f(fmaf(bf_lo(v.z), sc[c+4], sh[c+4]));
    float x5 = gelu_f(fmaf(bf_hi(v.z), sc[c+5], sh[c+5]));
    float x6 = gelu_f(fmaf(bf_lo(v.w), sc[c+6], sh[c+6]));
    float x7 = gelu_f(fmaf(bf_hi(v.w), sc[c+7], sh[c+7]));
    fmac64(acc, w1g + (c+0)*64, x0);
    fmac64(acc, w1g + (c+1)*64, x1);
    fmac64(acc, w1g + (c+2)*64, x2);
    fmac64(acc, w1g + (c+3)*64, x3);
    fmac64(acc, w1g + (c+4)*64, x4);
    fmac64(acc, w1g + (c+5)*64, x5);
    fmac64(acc, w1g + (c+6)*64, x6);
    fmac64(acc, w1g + (c+7)*64, x7);
    v = vn;
  }
#pragma unroll
  for (int q = 0; q < 8; ++q) {
    uint4 pk;
    pk.x = bfpack(acc[q*8+0], acc[q*8+1]);
    pk.y = bfpack(acc[q*8+2], acc[q*8+3]);
    pk.z = bfpack(acc[q*8+4], acc[q*8+5]);
    pk.w = bfpack(acc[q*8+6], acc[q*8+7]);
    xr[q] = pk;
  }
  block_colsum64(acc, sbuf, bsum, bssq, 0);
  if (tid < 64) {
    atomicAdd(&stat1[tid], bsum[tid]);
    atomicAdd(&stat1[64+tid], bssq[tid]);
  }
}

template<bool STORE_H2>
__global__ __launch_bounds__(256,2) void p2_kernel(
    ushort* X, ushort* __restrict__ H2, const float* __restrict__ wT,
    const float* __restrict__ stat1, const float* __restrict__ g1,
    const float* __restrict__ be1, const float* __restrict__ b2,
    float* __restrict__ stat2)
{
  __shared__ float sbuf[4352];
  __shared__ float bsum[128], bssq[128];
  __shared__ float sc[64], sh[64], b2s[128];
  const float* __restrict__ w2g = wT + W2T_OFF;
  const int tid = threadIdx.x;
  if (tid < 64) {
    float m1 = stat1[tid]*INV_NPTS;
    float v1 = stat1[64+tid]*INV_NPTS - m1*m1;
    float s1 = (1.0f/sqrtf(v1 + BN_EPS)) * g1[tid];
    sc[tid] = s1; sh[tid] = be1[tid] - m1*s1;
  }
  if (tid < 128) { b2s[tid] = b2[tid]; bsum[tid] = 0.f; bssq[tid] = 0.f; }
  __syncthreads();
  const int p = blockIdx.x*256 + tid;
  uint4* xr = (uint4*)(X + (size_t)p*64);
  float acc[128];
#pragma unroll
  for (int d = 0; d < 128; ++d) acc[d] = b2s[d];
  uint4 v = xr[0];
#pragma unroll 1
  for (int ch = 0; ch < 8; ++ch) {
    const int nc = (ch < 7) ? ch + 1 : 7;
    uint4 vn = xr[nc];
    const int c = ch*8;
    float x0 = gelu_f(fmaf(bf_lo(v.x), sc[c+0], sh[c+0]));
    float x1 = gelu_f(fmaf(bf_hi(v.x), sc[c+1], sh[c+1]));
    float x2 = gelu_f(fmaf(bf_lo(v.y), sc[c+2], sh[c+2]));
    float x3 = gelu_f(fmaf(bf_hi(v.y), sc[c+3], sh[c+3]));
    float x4 = gelu_f(fmaf(bf_lo(v.z), sc[c+4], sh[c+4]));
    float x5 = gelu_f(fmaf(bf_hi(v.z), sc[c+5], sh[c+5]));
    float x6 = gelu_f(fmaf(bf_lo(v.w), sc[c+6], sh[c+6]));
    float x7 = gelu_f(fmaf(bf_hi(v.w), sc[c+7], sh[c+7]));
    if (!STORE_H2) {
      uint4 pk;
      pk.x = bfpack(x0, x1); pk.y = bfpack(x2, x3);
      pk.z = bfpack(x4, x5); pk.w = bfpack(x6, x7);
      xr[ch] = pk;
    }
    fmac128(acc, w2g + (c+0)*128, x0);
    fmac128(acc, w2g + (c+1)*128, x1);
    fmac128(acc, w2g + (c+2)*128, x2);
    fmac128(acc, w2g + (c+3)*128, x3);
    fmac128(acc, w2g + (c+4)*128, x4);
    fmac128(acc, w2g + (c+5)*128, x5);
    fmac128(acc, w2g + (c+6)*128, x6);
    fmac128(acc, w2g + (c+7)*128, x7);
    v = vn;
  }
  if (STORE_H2) {
    uint4* hr = (uint4*)(H2 + (size_t)p*128);
#pragma unroll
    for (int q = 0; q < 16; ++q) {
      uint4 pk;
      pk.x = bfpack(acc[q*8+0], acc[q*8+1]);
      pk.y = bfpack(acc[q*8+2], acc[q*8+3]);
      pk.z = bfpack(acc[q*8+4], acc[q*8+5]);
      pk.w = bfpack(acc[q*8+6], acc[q*8+7]);
      hr[q] = pk;
    }
  }
#pragma unroll
  for (int half = 0; half < 2; ++half) {
    float tmp[64];
#pragma unroll
    for (int d = 0; d < 64; ++d) tmp[d] = acc[half*64 + d];
    block_colsum64(tmp, sbuf, bsum, bssq, half*64);
  }
  if (tid < 128) {
    atomicAdd(&stat2[tid], bsum[tid]);
    atomicAdd(&stat2[128+tid], bssq[tid]);
  }
}

__global__ __launch_bounds__(128) void fbig_kernel(
    const ushort* __restrict__ H2, const float* __restrict__ stat2,
    const float* __restrict__ g2, const float* __restrict__ be2,
    float* __restrict__ out_feat)
{
  const int d = threadIdx.x;
  const int bs = blockIdx.x;
  const float mean = stat2[d] * INV_NPTS;
  const float var  = stat2[128+d] * INV_NPTS - mean*mean;
  const float scale = (1.0f/sqrtf(var + BN_EPS)) * g2[d];
  const float shift = be2[d] - mean*scale;
  const ushort* rp = H2 + (size_t)bs*NK*128 + d;
  float m = -3.4e38f;
#pragma unroll 4
  for (int k = 0; k < NK; ++k) {
    float t = __uint_as_float(((uint)rp[k*128]) << 16);
    m = fmaxf(m, gelu_f(fmaf(t, scale, shift)));
  }
  out_feat[(size_t)bs*128 + d] = m;
}

__global__ __launch_bounds__(256,2) void fsmall_kernel(
    const ushort* __restrict__ X, const float* __restrict__ wT,
    const float* __restrict__ b2, const float* __restrict__ stat2,
    const float* __restrict__ g2, const float* __restrict__ be2,
    float* __restrict__ out_feat)
{
  __shared__ float b2s[128], sc2[128], sh2[128];
  const float* __restrict__ w2g = wT + W2T_OFF;
  const int tid = threadIdx.x;
  if (tid < 128) {
    b2s[tid] = b2[tid];
    float m2 = stat2[tid]*INV_NPTS;
    float v2 = stat2[128+tid]*INV_NPTS - m2*m2;
    float s2 = (1.0f/sqrtf(v2 + BN_EPS)) * g2[tid];
    sc2[tid] = s2; sh2[tid] = be2[tid] - m2*s2;
  }
  __syncthreads();
  const int p = blockIdx.x*256 + tid;
  const int bs = p >> 5;
  const uint4* xr = (const uint4*)(X + (size_t)p*64);
  float acc[128];
#pragma unroll
  for (int d = 0; d < 128; ++d) acc[d] = b2s[d];
  uint4 v = xr[0];
#pragma unroll 1
  for (int ch = 0; ch < 8; ++ch) {
    const int nc = (ch < 7) ? ch + 1 : 7;
    uint4 vn = xr[nc];
    const int c = ch*8;
    fmac128(acc, w2g + (c+0)*128, bf_lo(v.x));
    fmac128(acc, w2g + (c+1)*128, bf_hi(v.x));
    fmac128(acc, w2g + (c+2)*128, bf_lo(v.y));
    fmac128(acc, w2g + (c+3)*128, bf_hi(v.y));
    fmac128(acc, w2g + (c+4)*128, bf_lo(v.z));
    fmac128(acc, w2g + (c+5)*128, bf_hi(v.z));
    fmac128(acc, w2g + (c+6)*128, bf_lo(v.w));
    fmac128(acc, w2g + (c+7)*128, bf_hi(v.w));
    v = vn;
  }
#pragma unroll
  for (int d = 0; d < 128; ++d) {
    float y = gelu_f(fmaf(acc[d], sc2[d], sh2[d]));
#pragma unroll
    for (int m = 1; m < 32; m <<= 1) y = fmaxf(y, __shfl_xor(y, m));
    acc[d] = y;
  }
  if ((tid & 31) == 0) {
    float4* op = (float4*)(out_feat + (size_t)bs*128);
#pragma unroll
    for (int i = 0; i < 32; ++i)
      op[i] = make_float4(acc[i*4], acc[i*4+1], acc[i*4+2], acc[i*4+3]);
  }
}

// ================================================================ fallback (recompute path; unchanged)
__device__ __forceinline__ void chain_to_x2(
    const float* __restrict__ xyz, const float* __restrict__ feat,
    const float* __restrict__ centers, const int* __restrict__ gidx,
    const float* wsh, float* sbuf, const float* prm, int p, float (&x2)[64])
{
  float acc0[64];
  layer0(xyz, feat, centers, gidx, wsh, prm, p, acc0);
#pragma unroll
  for (int c = 0; c < 64; ++c) acc0[c] = gelu_f(fmaf(acc0[c], prm[64+c], prm[128+c]));
#pragma unroll
  for (int d = 0; d < 64; ++d) x2[d] = prm[192+d];
  float* xrow = sbuf + threadIdx.x*17;
#pragma unroll
  for (int cc = 0; cc < 4; ++cc) {
#pragma unroll
    for (int j = 0; j < 16; ++j) xrow[j] = acc0[cc*16 + j];
#pragma unroll 1
    for (int cj = 0; cj < 16; ++cj)
      fmac64(x2, wsh + W1T_OFF + (cc*16+cj)*64, xrow[cj]);
  }
#pragma unroll
  for (int c = 0; c < 64; ++c) x2[c] = gelu_f(fmaf(x2[c], prm[256+c], prm[320+c]));
}

__global__ __launch_bounds__(256,2) void s0_kernel(
    const float* __restrict__ xyz, const float* __restrict__ feat,
    const float* __restrict__ centers, const int* __restrict__ gidx,
    const float* __restrict__ wT, const float* __restrict__ b0,
    float* __restrict__ stat0)
{
  __shared__ float wsh[4288];
  __shared__ float sbuf[4352];
  __shared__ float bsum[64], bssq[64], b0s[64];
  const int tid = threadIdx.x;
  for (int i = tid; i < 1072; i += 256) ((float4*)wsh)[i] = ((const float4*)wT)[i];
  if (tid < 64) { bsum[tid] = 0.f; bssq[tid] = 0.f; b0s[tid] = b0[tid]; }
  __syncthreads();
  const int p = blockIdx.x*256 + tid;
  float acc[64];
  layer0(xyz, feat, centers, gidx, wsh, b0s, p, acc);
  block_colsum64(acc, sbuf, bsum, bssq, 0);
  if (tid < 64) {
    atomicAdd(&stat0[tid], bsum[tid]);
    atomicAdd(&stat0[64+tid], bssq[tid]);
  }
}

__global__ __launch_bounds__(256,2) void s1_kernel(
    const float* __restrict__ xyz, const float* __restrict__ feat,
    const float* __restrict__ centers, const int* __restrict__ gidx,
    const float* __restrict__ wT, const float* __restrict__ stat0,
    const float* __restrict__ g0, const float* __restrict__ be0,
    const float* __restrict__ b0, const float* __restrict__ b1,
    float* __restrict__ stat1)
{
  __shared__ float wsh[8384];
  __shared__ float sbuf[4352];
  __shared__ float bsum[64], bssq[64];
  __shared__ float prm[256];
  const int tid = threadIdx.x;
  for (int i = tid; i < 2096; i += 256) ((float4*)wsh)[i] = ((const float4*)wT)[i];
  if (tid < 64) {
    float m0 = stat0[tid]*INV_NPTS;
    float v0 = stat0[64+tid]*INV_NPTS - m0*m0;
    float sc0 = (1.0f/sqrtf(v0 + BN_EPS)) * g0[tid];
    prm[tid] = b0[tid]; prm[64+tid] = sc0; prm[128+tid] = be0[tid] - m0*sc0;
    prm[192+tid] = b1[tid];
    bsum[tid] = 0.f; bssq[tid] = 0.f;
  }
  __syncthreads();
  const int p = blockIdx.x*256 + tid;
  float acc0[64];
  layer0(xyz, feat, centers, gidx, wsh, prm, p, acc0);
#pragma unroll
  for (int c = 0; c < 64; ++c) acc0[c] = gelu_f(fmaf(acc0[c], prm[64+c], prm[128+c]));
  float acc1[64];
#pragma unroll
  for (int d = 0; d < 64; ++d) acc1[d] = prm[192+d];
  float* xrow = sbuf + tid*17;
#pragma unroll
  for (int cc = 0; cc < 4; ++cc) {
#pragma unroll
    for (int j = 0; j < 16; ++j) xrow[j] = acc0[cc*16 + j];
#pragma unroll 1
    for (int cj = 0; cj < 16; ++cj)
      fmac64(acc1, wsh + W1T_OFF + (cc*16+cj)*64, xrow[cj]);
  }
  block_colsum64(acc1, sbuf, bsum, bssq, 0);
  if (tid < 64) {
    atomicAdd(&stat1[tid], bsum[tid]);
    atomicAdd(&stat1[64+tid], bssq[tid]);
  }
}

__global__ __launch_bounds__(256,2) void s2_kernel(
    const float* __restrict__ xyz, const float* __restrict__ feat,
    const float* __restrict__ centers, const int* __restrict__ gidx,
    const float* __restrict__ wT,
    const float* __restrict__ stat0, const float* __restrict__ g0,
    const float* __restrict__ be0, const float* __restrict__ b0,
    const float* __restrict__ b1, const float* __restrict__ stat1,
    const float* __restrict__ g1, const float* __restrict__ be1,
    const float* __restrict__ b2, float* __restrict__ stat2)
{
  __shared__ float wsh[8384];
  __shared__ float sbuf[4352];
  __shared__ float bsum[128], bssq[128];
  __shared__ float prm[512];
  const int tid = threadIdx.x;
  for (int i = tid; i < 2096; i += 256) ((float4*)wsh)[i] = ((const float4*)wT)[i];
  if (tid < 64) {
    float m0 = stat0[tid]*INV_NPTS;
    float v0 = stat0[64+tid]*INV_NPTS - m0*m0;
    float sc0 = (1.0f/sqrtf(v0 + BN_EPS)) * g0[tid];
    prm[tid] = b0[tid]; prm[64+tid] = sc0; prm[128+tid] = be0[tid] - m0*sc0;
    float m1 = stat1[tid]*INV_NPTS;
    float v1 = stat1[64+tid]*INV_NPTS - m1*m1;
    float sc1 = (1.0f/sqrtf(v1 + BN_EPS)) * g1[tid];
    prm[192+tid] = b1[tid]; prm[256+tid] = sc1; prm[320+tid] = be1[tid] - m1*sc1;
  }
  if (tid < 128) { prm[384+tid] = b2[tid]; bsum[tid] = 0.f; bssq[tid] = 0.f; }
  __syncthreads();
  const int p = blockIdx.x*256 + tid;
  float x2[64];
  chain_to_x2(xyz, feat, centers, gidx, wsh, sbuf, prm, p, x2);
  __syncthreads();
  for (int i = tid; i < 2048; i += 256)
    ((float4*)wsh)[i] = ((const float4*)(wT + W2T_OFF))[i];
  __syncthreads();
  float* xrow = sbuf + tid*17;
#pragma unroll 1
  for (int half = 0; half < 2; ++half) {
    float a2[64];
#pragma unroll
    for (int d = 0; d < 64; ++d) a2[d] = prm[384 + half*64 + d];
#pragma unroll
    for (int cc = 0; cc < 4; ++cc) {
#pragma unroll
      for (int j = 0; j < 16; ++j) xrow[j] = x2[cc*16 + j];
#pragma unroll 1
      for (int cj = 0; cj < 16; ++cj)
        fmac64(a2, wsh + (cc*16+cj)*128 + half*64, xrow[cj]);
    }
    block_colsum64(a2, sbuf, bsum, bssq, half*64);
  }
  if (tid < 128) {
    atomicAdd(&stat2[tid], bsum[tid]);
    atomicAdd(&stat2[128+tid], bssq[tid]);
  }
}

__global__ __launch_bounds__(256,2) void fin_kernel(
    const float* __restrict__ xyz, const float* __restrict__ feat,
    const float* __restrict__ centers, const int* __restrict__ gidx,
    const float* __restrict__ wT,
    const float* __restrict__ stat0, const float* __restrict__ g0,
    const float* __restrict__ be0, const float* __restrict__ b0,
    const float* __restrict__ b1, const float* __restrict__ stat1,
    const float* __restrict__ g1, const float* __restrict__ be1,
    const float* __restrict__ b2, const float* __restrict__ stat2,
    const float* __restrict__ g2, const float* __restrict__ be2,
    float* __restrict__ out_feat)
{
  __shared__ float wsh[8384];
  __shared__ float sbuf[4352];
  __shared__ float prm[768];
  const int tid = threadIdx.x;
  for (int i = tid; i < 2096; i += 256) ((float4*)wsh)[i] = ((const float4*)wT)[i];
  if (tid < 64) {
    float m0 = stat0[tid]*INV_NPTS;
    float v0 = stat0[64+tid]*INV_NPTS - m0*m0;
    float sc0 = (1.0f/sqrtf(v0 + BN_EPS)) * g0[tid];
    prm[tid] = b0[tid]; prm[64+tid] = sc0; prm[128+tid] = be0[tid] - m0*sc0;
    float m1 = stat1[tid]*INV_NPTS;
    float v1 = stat1[64+tid]*INV_NPTS - m1*m1;
    float sc1 = (1.0f/sqrtf(v1 + BN_EPS)) * g1[tid];
    prm[192+tid] = b1[tid]; prm[256+tid] = sc1; prm[320+tid] = be1[tid] - m1*sc1;
  }
  if (tid < 128) {
    prm[384+tid] = b2[tid];
    float m2 = stat2[tid]*INV_NPTS;
    float v2 = stat2[128+tid]*INV_NPTS - m2*m2;
    float sc2 = (1.0f/sqrtf(v2 + BN_EPS)) * g2[tid];
    prm[512+tid] = sc2; prm[640+tid] = be2[tid] - m2*sc2;
  }
  __syncthreads();
  const int p = blockIdx.x*256 + tid;
  const int b = p >> 15;
  const int s = (p & 32767) >> 5;
  float x2[64];
  chain_to_x2(xyz, feat, centers, gidx, wsh, sbuf, prm, p, x2);
  __syncthreads();
  for (int i = tid; i < 2048; i += 256)
    ((float4*)wsh)[i] = ((const float4*)(wT + W2T_OFF))[i];
  __syncthreads();
  float* xrow = sbuf + tid*17;
#pragma unroll 1
  for (int half = 0; half < 2; ++half) {
    float a2[64];
#pragma unroll
    for (int d = 0; d < 64; ++d) a2[d] = prm[384 + half*64 + d];
#pragma unroll
    for (int cc = 0; cc < 4; ++cc) {
#pragma unroll
      for (int j = 0; j < 16; ++j) xrow[j] = x2[cc*16 + j];
#pragma unroll 1
      for (int cj = 0; cj < 16; ++cj)
        fmac64(a2, wsh + (cc*16+cj)*128 + half*64, xrow[cj]);
    }
#pragma unroll
    for (int d = 0; d < 64; ++d) {
      float y = gelu_f(fmaf(a2[d], prm[512 + half*64 + d], prm[640 + half*64 + d]));
#pragma unroll
      for (int m = 1; m < 32; m <<= 1) y = fmaxf(y, __shfl_xor(y, m));
      a2[d] = y;
    }
    if ((tid & 31) == 0) {
      float4* op = (float4*)(out_feat + ((size_t)(b*NS + s))*128 + half*64);
#pragma unroll
      for (int i = 0; i < 16; ++i)
        op[i] = make_float4(a2[i*4], a2[i*4+1], a2[i*4+2], a2[i*4+3]);
    }
  }
}

// ================================================================ launch
extern "C" void kernel_launch(void* const* d_in, const int* in_sizes, int n_in,
                              void* d_out, int out_size, void* d_ws, size_t ws_size,
                              hipStream_t stream) {
  (void)in_sizes; (void)n_in; (void)out_size;
  const float* xyz      = (const float*)d_in[0];
  const float* features = (const float*)d_in[1];
  const float* w0  = (const float*)d_in[2];
  const float* b0  = (const float*)d_in[3];
  const float* g0  = (const float*)d_in[4];
  const float* be0 = (const float*)d_in[5];
  const float* w1  = (const float*)d_in[6];
  const float* b1  = (const float*)d_in[7];
  const float* g1  = (const float*)d_in[8];
  const float* be1 = (const float*)d_in[9];
  const float* w2  = (const float*)d_in[10];
  const float* b2  = (const float*)d_in[11];
  const float* g2  = (const float*)d_in[12];
  const float* be2 = (const float*)d_in[13];

  float* out = (float*)d_out;
  float* out_newxyz = out;                 // (16,1024,3)
  float* out_feat   = out + NB*NS*3;       // (16,1024,128)

  char* ws = (char*)d_ws;
  size_t off = 0;
  float* centers   = (float*)(ws + off); off += (size_t)NB*NS*3*4;
  int*   group_idx = (int*)(ws + off);   off += (size_t)NPTS*4;
  float* stats     = (float*)(ws + off); off += 512*4;
  off = (off + 255) & ~(size_t)255;
  float* wT        = (float*)(ws + off); off += (size_t)WT_TOTAL*4;
  off = (off + 255) & ~(size_t)255;
  const size_t base_end = off;
  const size_t X_bytes  = (size_t)NPTS*64*2;    // 67.1 MB
  const size_t H2_bytes = (size_t)NPTS*128*2;   // 134.2 MB
  const size_t F0_bytes = (size_t)NROWS*64*4;   // 16.8 MB
  ushort* X  = (ushort*)(ws + base_end);
  ushort* H2 = (ushort*)(ws + base_end + X_bytes);

  // Tier thresholds unchanged; F0 appended after the active tier's buffers.
  const bool tier_big   = ws_size >= base_end + X_bytes + H2_bytes;
  const bool tier_small = !tier_big && ws_size >= base_end + X_bytes;
  if (ws_size < base_end) return;
  const size_t f0_off = tier_big ? base_end + X_bytes + H2_bytes
                                 : base_end + X_bytes;
  const bool use_f0 = (tier_big || tier_small) && (ws_size >= f0_off + F0_bytes);
  float* F0 = (float*)(ws + f0_off);

  float* stat0 = stats;
  float* stat1 = stats + 128;
  float* stat2 = stats + 256;

  (void)hipMemsetAsync(stats, 0, 2048, stream);
  prep_kernel<<<65, 256, 0, stream>>>(w0, w1, w2, wT);
  if (use_f0)
    f0_kernel<<<NROWS/256, 256, 0, stream>>>(features, wT, b0, F0);
  fps_kernel<<<NB, FPS_T, 0, stream>>>(xyz, centers, out_newxyz);
  ball_kernel<<<NB*64, 256, 0, stream>>>(xyz, centers, group_idx);

  if (tier_big || tier_small) {
    if (use_f0)
      p0_kernel<true><<<NPTS/256, 256, 0, stream>>>(xyz, features, centers, group_idx,
                                                    wT, b0, F0, X, stat0);
    else
      p0_kernel<false><<<NPTS/256, 256, 0, stream>>>(xyz, features, centers, group_idx,
                                                     wT, b0, F0, X, stat0);
    p1_kernel<<<NPTS/256, 256, 0, stream>>>(X, wT, stat0, g0, be0, b1, stat1);
    if (tier_big) {
      p2_kernel<true><<<NPTS/256, 256, 0, stream>>>(X, H2, wT, stat1, g1, be1, b2, stat2);
      fbig_kernel<<<NB*NS, 128, 0, stream>>>(H2, stat2, g2, be2, out_feat);
    } else {
      p2_kernel<false><<<NPTS/256, 256, 0, stream>>>(X, H2, wT, stat1, g1, be1, b2, stat2);
      fsmall_kernel<<<NPTS/256, 256, 0, stream>>>(X, wT, b2, stat2, g2, be2, out_feat);
    }
  } else {
    s0_kernel<<<NPTS/256, 256, 0, stream>>>(xyz, features, centers, group_idx, wT, b0, stat0);
    s1_kernel<<<NPTS/256, 256, 0, stream>>>(xyz, features, centers, group_idx, wT,
                                            stat0, g0, be0, b0, b1, stat1);
    s2_kernel<<<NPTS/256, 256, 0, stream>>>(xyz, features, centers, group_idx, wT,
                                            stat0, g0, be0, b0, b1, stat1, g1, be1, b2, stat2);
    fin_kernel<<<NPTS/256, 256, 0, stream>>>(xyz, features, centers, group_idx, wT,
                                             stat0, g0, be0, b0, b1, stat1, g1, be1, b2,
                                             stat2, g2, be2, out_feat);
  }
}